// Round 23
// baseline (308.365 us; speedup 1.0000x reference)
//
#include <hip/hip_runtime.h>

// Locally connected layer:
// out[b,o,h,w] = sum_{c,i,j} x[b,c,h+i,w+j] * W[o,c,h,w,i,j] + bias[o,h,w]
// x: [32,32,64,64] f32, W: [64,32,62,62,3,3] f32, bias: [64,62,62] f32
// out: [32,64,62,62] f32
//
// R23 = R21 structure + channel split (C into 2 halves of 16) with atomic
// f32 accumulation. R22 lesson: TLP bought by duplicating work regresses.
// Channel split PARTITIONS x and W reads (zero duplication; FETCH
// unchanged), doubles the grid to 1984 blocks (fills the 4-blocks/CU LDS
// cap -> ~16 waves/CU), halves block runtime (tail). fp32 a+b is
// commutative bit-exactly -> 2-way atomic accumulation is deterministic.
// out zeroed by a grid-stride kernel first (same stream, ordered); bias
// added by chalf==0 only; unsafeAtomicAdd = hw global_atomic_add_f32.
// Per-channel pipeline identical to R21 (140us bench best): pin-before-
// FENCE (R20), x-oldest/gll-youngest FIFO (R21), coalesced W gll->LDS
// depth-2 (R10/R16), DPP halo 0x101 (R8), chunked XCD swizzle (R3).

#define C_  32
#define CH_ 16
#define B_  32
#define O_  64
#define H_  64
#define W_  64
#define OH_ 62
#define OW_ 62

typedef float vfloat2 __attribute__((ext_vector_type(2)));
typedef float vfloat4 __attribute__((ext_vector_type(4)));

#define GLL4(gaddr, laddr)                                                      \
    __builtin_amdgcn_global_load_lds(                                           \
        (const __attribute__((address_space(1))) void*)(gaddr),                 \
        (__attribute__((address_space(3))) void*)(laddr), 4, 0, 0)

// dst[lane] = src[lane+1] within each 16-lane row (validated R8)
__device__ __forceinline__ float dpp_nextlane(float v) {
    return __int_as_float(__builtin_amdgcn_update_dpp(
        0, __float_as_int(v), 0x101, 0xf, 0xf, true));
}

#define WAITV(n) do {                                                           \
        asm volatile("s_waitcnt vmcnt(" #n ")" ::: "memory");                   \
        __builtin_amdgcn_sched_barrier(0);                                      \
    } while (0)

#define FENCE() __builtin_amdgcn_sched_barrier(0)

__global__ __launch_bounds__(256)
void zero_kernel(float4* __restrict__ p, int n4) {
    int i = blockIdx.x * blockDim.x + threadIdx.x;
    const int stride = gridDim.x * blockDim.x;
    float4 z; z.x = 0.f; z.y = 0.f; z.z = 0.f; z.w = 0.f;
    for (; i < n4; i += stride) p[i] = z;
}

__global__ __launch_bounds__(256)
void lcl_kernel(const float* __restrict__ x,
                const float* __restrict__ Wt,
                const float* __restrict__ bias,
                float* __restrict__ out) {
    // W rows: [2 buffers][4 waves][2 o's][576 floats] = 36864 B (4 blk/CU)
    __shared__ float ldsW[2][4][2][576];

    // ---- chunked XCD swizzle (hw: XCD = blockIdx.x % 8); 1984 = 8 * 248.
    // chalf is the fastest logical bit -> the two channel-halves of one
    // (og,h,bhalf) are XCD-adjacent (atomics meet in the same L2).
    const int i0      = blockIdx.x;
    const int logical = (i0 & 7) * 248 + (i0 >> 3);
    const int chalf   = logical & 1;                 // channels 0-15 / 16-31
    const int l2      = logical >> 1;
    const int bhalf   = l2 & 1;                      // batches 0-15 / 16-31
    const int pair    = l2 >> 1;                     // 0..495
    const int og      = pair & 7;                    // o-octet (fast)
    const int h       = pair >> 3;                   // 0..61
    const int c0      = chalf * CH_;

    const int wv_i = threadIdx.x >> 6;               // wave 0..3
    const int o0   = (og << 3) + (wv_i << 1);        // this wave: o0, o0+1
    const int lane = threadIdx.x & 63;
    const int wg   = lane & 15;                      // w0 = 4*wg
    const int bg   = lane >> 4;                      // 4 batches per bg
    const int w0   = wg * 4;
    const int b0   = bhalf * 16 + bg * 4;
    const bool full = (wg < 15);                     // wg15 stores only w=60,61

    float acc0[4][4], acc1[4][4];
#pragma unroll
    for (int bi = 0; bi < 4; ++bi)
#pragma unroll
        for (int wi = 0; wi < 4; ++wi) { acc0[bi][wi] = 0.f; acc1[bi][wi] = 0.f; }

    // W row bases (floats): o*C*34596 + h*558 (+ global c * 34596)
    const long wrow0 = (long)o0 * (C_ * 34596) + (long)h * 558 + (long)c0 * 34596;
    const long wrow1 = wrow0 + (long)C_ * 34596;     // o0+1

    // x byte base for (b0, h, w0) at channel c0
    const char* xb0 = (const char*)x + (unsigned)b0 * 524288u
                      + (unsigned)c0 * 16384u
                      + (unsigned)h * 256u + (unsigned)wg * 16u;

    // stage both 2232-B W rows coalesced (2 x 9 gll dword; tail covers
    // [1976,2232), overlap [1976,2048) double-written with same data).
#define STAGE_W2(buf, cidx) do {                                                \
        const char* s0_ = (const char*)(Wt + wrow0 + (long)(cidx) * 34596);     \
        const char* s1_ = (const char*)(Wt + wrow1 + (long)(cidx) * 34596);     \
        char* d0_ = (char*)&ldsW[buf][wv_i][0][0];                              \
        char* d1_ = (char*)&ldsW[buf][wv_i][1][0];                              \
        _Pragma("unroll")                                                       \
        for (int k_ = 0; k_ < 8; ++k_)                                          \
            GLL4(s0_ + k_ * 256 + lane * 4, d0_ + k_ * 256);                    \
        GLL4(s0_ + 1976 + lane * 4, d0_ + 1976);                                \
        _Pragma("unroll")                                                       \
        for (int k_ = 0; k_ < 8; ++k_)                                          \
            GLL4(s1_ + k_ * 256 + lane * 4, d1_ + k_ * 256);                    \
        GLL4(s1_ + 1976 + lane * 4, d1_ + 1976);                                \
    } while (0)

    // lane's 36 W floats for o-slot oo_ (9 ds_read_b128; 144-B lane stride =
    // 2-way alias + 4-way bg broadcast = cheap). wg=15 reads pad, not stored.
#define DSREAD_W(buf, oo_) do {                                                 \
        const char* r_ = (const char*)&ldsW[buf][wv_i][oo_][0] + wg * 144;      \
        _Pragma("unroll")                                                       \
        for (int q_ = 0; q_ < 9; ++q_)                                          \
            wq[q_] = *reinterpret_cast<const vfloat4*>(r_ + q_ * 16);           \
    } while (0)

#define WQ(t) (wq[(t) >> 2][(t) & 3])

    // issue 3 float4 rows of batch b0+bi_ for LOCAL channel cidx into slot s_
#define XLD(s_, cidx, bi_) do {                                                 \
        const char* p_ = xb0 + (unsigned)(bi_) * 524288u                        \
                         + (unsigned)(cidx) * 16384u;                           \
        xv##s_[0] = *reinterpret_cast<const float4*>(p_);                       \
        xv##s_[1] = *reinterpret_cast<const float4*>(p_ + 256);                 \
        xv##s_[2] = *reinterpret_cast<const float4*>(p_ + 512);                 \
    } while (0)

    // expand slot s_ via DPP halo, 36 FMAs into ACC[bi_]
#define FMA1(ACC, s_, bi_) do {                                                 \
        float xr_[3][6];                                                        \
        _Pragma("unroll")                                                       \
        for (int r_ = 0; r_ < 3; ++r_) {                                        \
            xr_[r_][0] = xv##s_[r_].x; xr_[r_][1] = xv##s_[r_].y;               \
            xr_[r_][2] = xv##s_[r_].z; xr_[r_][3] = xv##s_[r_].w;               \
            xr_[r_][4] = dpp_nextlane(xv##s_[r_].x);                            \
            xr_[r_][5] = dpp_nextlane(xv##s_[r_].y);                            \
        }                                                                       \
        _Pragma("unroll")                                                       \
        for (int wi_ = 0; wi_ < 4; ++wi_)                                       \
        _Pragma("unroll")                                                       \
        for (int ii_ = 0; ii_ < 3; ++ii_)                                       \
        _Pragma("unroll")                                                       \
        for (int j_ = 0; j_ < 3; ++j_)                                          \
            ACC[bi_][wi_] = fmaf(xr_[ii_][wi_ + j_],                            \
                                 WQ(wi_ * 9 + ii_ * 3 + j_), ACC[bi_][wi_]);    \
    } while (0)

    vfloat4 wq[9];
    float4  xvA[3], xvB[3], xvC[3], xvD[3];

    // ---- prologue: depth-2 W prefetch, then x(0) as the oldest-next VMEM
    STAGE_W2(0, 0);
    STAGE_W2(1, 1);
    XLD(A, 0, 0);
    XLD(B, 0, 1);
    XLD(C, 0, 2);
    XLD(D, 0, 3);

    for (int c = 0; c < CH_; ++c) {
        const int p = c & 1;
        // invariant: outstanding = gll(c) 18 + x(c) 12 + gll(c+1) 18 = 48.
        // vmcnt(30) retires exactly gll(c) (staged 2 channels ago -> ~free).
        WAITV(30);
        DSREAD_W(p, 0);                   // wq := o0 row
        FENCE();
        FMA1(acc0, A, 0);                 // waits x(c) only (oldest in queue)
        FMA1(acc0, B, 1);
        FMA1(acc0, C, 2);
        FMA1(acc0, D, 3);
        FENCE();
        DSREAD_W(p, 1);                   // wq := o1 row (same regs)
        FENCE();
        FMA1(acc1, A, 0);
        FMA1(acc1, B, 1);
        FMA1(acc1, C, 2);
        FMA1(acc1, D, 3);
        FENCE();
        if (c + 1 < CH_) {                // x(c+1): oldest VMEM of channel c+1
            XLD(A, c + 1, 0);
            XLD(B, c + 1, 1);
            XLD(C, c + 1, 2);
            XLD(D, c + 1, 3);
        }
        FENCE();
        {                                 // gll(c+2): YOUNGEST. Clamped dup at
            const int cn = (c + 2 < CH_) ? (c + 2) : (CH_ - 1); // tail keeps
            STAGE_W2(p, cn);              // the count invariant; buf p was
        }                                 // fully ds_read above (no race).
    }

    // ---- epilogue: atomic f32 accumulation (2 channel-halves meet here).
    // bias added by chalf==0 only. a+b is order-independent in fp32.
#pragma unroll
    for (int oo = 0; oo < 2; ++oo) {
        const int oc = o0 + oo;
        float bv[4] = {0.f, 0.f, 0.f, 0.f};
        if (chalf == 0) {
            const float* brow = bias + ((long)oc * OH_ + h) * OW_ + w0;
            bv[0] = brow[0]; bv[1] = brow[1];
            if (full) { bv[2] = brow[2]; bv[3] = brow[3]; }
        }
        const int nw = full ? 4 : 2;
#pragma unroll
        for (int bi = 0; bi < 4; ++bi) {
            const float* a_ = oo ? acc1[bi] : acc0[bi];
            float* orow = out + (((long)(b0 + bi) * O_ + oc) * OH_ + h) * OW_ + w0;
#pragma unroll
            for (int wi = 0; wi < 4; ++wi)
                if (wi < nw) unsafeAtomicAdd(orow + wi, a_[wi] + bv[wi]);
        }
    }

#undef STAGE_W2
#undef DSREAD_W
#undef WQ
#undef XLD
#undef FMA1
}

extern "C" void kernel_launch(void* const* d_in, const int* in_sizes, int n_in,
                              void* d_out, int out_size, void* d_ws, size_t ws_size,
                              hipStream_t stream) {
    const float* x    = (const float*)d_in[0];
    const float* Wt   = (const float*)d_in[1];
    const float* bias = (const float*)d_in[2];
    float* out        = (float*)d_out;

    // zero out (same stream -> ordered before the atomics)
    zero_kernel<<<2048, 256, 0, stream>>>((float4*)d_out, out_size / 4);

    dim3 grid(1984);   // (62 h x 8 og x 2 bhalf x 2 chalf), XCD-swizzled
    dim3 block(256);
    lcl_kernel<<<grid, block, 0, stream>>>(x, Wt, bias, out);
}

// Round 24
// 142.820 us; speedup vs baseline: 2.1591x; 2.1591x over previous
//
#include <hip/hip_runtime.h>

// Locally connected layer:
// out[b,o,h,w] = sum_{c,i,j} x[b,c,h+i,w+j] * W[o,c,h,w,i,j] + bias[o,h,w]
// x: [32,32,64,64] f32, W: [64,32,62,62,3,3] f32, bias: [64,62,62] f32
// out: [32,64,62,62] f32
//
// R24 = R21 (best: 140us bench) + s_setprio(1) around FMA clusters (T5).
// R23 post-mortem: atomic accumulation = 262 MB write traffic (cross-XCD
// L2 ping-pong), reverted. The barrier-free multi-wave structure has wave
// role-diversity (some waves in gll/XLD bursts, some in FMA blocks) ->
// setprio's regime (m191: +4-7% attn; null only in lockstep schedules).
// Occupancy counter distrusted (gfx94x fallback; tracks ~1/VGPR); the
// closing model: 4 waves/EU resident, ~1400cy VALU/wave-channel -> 39%
// VALUBusy as measured. Pipeline is FIFO-clean:
//   WAITV(30) [retires gll(c), 2 channels old] -> DSREAD o0 -> FMA acc0
//   (waits only x(c), issued end of c-1) -> DSREAD o1 -> FMA acc1 ->
//   XLD(c+1) -> STAGE_W2(c+2) youngest.
// Validated: pin-before-FENCE (R20: VGPR 64->104, 240->180us), batch-split
// twins (R20), 2 o's/wave, coalesced W gll->LDS (R10: 421->242us),
// barrier-free (R12), DPP halo 0x101 (R8), chunked XCD swizzle (R3),
// nontemporal stores, plain launch_bounds (min-waves clause spills R4/R8).

#define C_  32
#define B_  32
#define O_  64
#define H_  64
#define W_  64
#define OH_ 62
#define OW_ 62

typedef float vfloat2 __attribute__((ext_vector_type(2)));
typedef float vfloat4 __attribute__((ext_vector_type(4)));

#define GLL4(gaddr, laddr)                                                      \
    __builtin_amdgcn_global_load_lds(                                           \
        (const __attribute__((address_space(1))) void*)(gaddr),                 \
        (__attribute__((address_space(3))) void*)(laddr), 4, 0, 0)

// dst[lane] = src[lane+1] within each 16-lane row (validated R8)
__device__ __forceinline__ float dpp_nextlane(float v) {
    return __int_as_float(__builtin_amdgcn_update_dpp(
        0, __float_as_int(v), 0x101, 0xf, 0xf, true));
}

#define WAITV(n) do {                                                           \
        asm volatile("s_waitcnt vmcnt(" #n ")" ::: "memory");                   \
        __builtin_amdgcn_sched_barrier(0);                                      \
    } while (0)

#define FENCE() __builtin_amdgcn_sched_barrier(0)

__global__ __launch_bounds__(256)
void lcl_kernel(const float* __restrict__ x,
                const float* __restrict__ Wt,
                const float* __restrict__ bias,
                float* __restrict__ out) {
    // W rows: [2 buffers][4 waves][2 o's][576 floats] = 36864 B
    __shared__ float ldsW[2][4][2][576];

    // ---- chunked XCD swizzle (hw: XCD = blockIdx.x % 8); 992 = 8 * 124
    const int i0      = blockIdx.x;
    const int logical = (i0 & 7) * 124 + (i0 >> 3);
    const int bhalf   = logical & 1;                 // twin: batches 0-15/16-31
    const int pair    = logical >> 1;                // 0..495
    const int og      = pair & 7;                    // o-octet (fast)
    const int h       = pair >> 3;                   // 0..61

    const int wv_i = threadIdx.x >> 6;               // wave 0..3
    const int o0   = (og << 3) + (wv_i << 1);        // this wave: o0, o0+1
    const int lane = threadIdx.x & 63;
    const int wg   = lane & 15;                      // w0 = 4*wg
    const int bg   = lane >> 4;                      // 4 batches per bg
    const int w0   = wg * 4;
    const int b0   = bhalf * 16 + bg * 4;
    const bool full = (wg < 15);                     // wg15 stores only w=60,61

    float acc0[4][4], acc1[4][4];
#pragma unroll
    for (int bi = 0; bi < 4; ++bi)
#pragma unroll
        for (int wi = 0; wi < 4; ++wi) { acc0[bi][wi] = 0.f; acc1[bi][wi] = 0.f; }

    // W row bases (floats): o*C*34596 + h*558
    const long wrow0 = (long)o0 * (C_ * 34596) + (long)h * 558;
    const long wrow1 = wrow0 + (long)C_ * 34596;     // o0+1

    // x byte base for (b0, h, w0)
    const char* xb0 = (const char*)x + (unsigned)b0 * 524288u
                      + (unsigned)h * 256u + (unsigned)wg * 16u;

    // stage both 2232-B W rows coalesced (2 x 9 gll dword; tail covers
    // [1976,2232), overlap [1976,2048) double-written with same data).
#define STAGE_W2(buf, cidx) do {                                                \
        const char* s0_ = (const char*)(Wt + wrow0 + (long)(cidx) * 34596);     \
        const char* s1_ = (const char*)(Wt + wrow1 + (long)(cidx) * 34596);     \
        char* d0_ = (char*)&ldsW[buf][wv_i][0][0];                              \
        char* d1_ = (char*)&ldsW[buf][wv_i][1][0];                              \
        _Pragma("unroll")                                                       \
        for (int k_ = 0; k_ < 8; ++k_)                                          \
            GLL4(s0_ + k_ * 256 + lane * 4, d0_ + k_ * 256);                    \
        GLL4(s0_ + 1976 + lane * 4, d0_ + 1976);                                \
        _Pragma("unroll")                                                       \
        for (int k_ = 0; k_ < 8; ++k_)                                          \
            GLL4(s1_ + k_ * 256 + lane * 4, d1_ + k_ * 256);                    \
        GLL4(s1_ + 1976 + lane * 4, d1_ + 1976);                                \
    } while (0)

    // lane's 36 W floats for o-slot oo_ (9 ds_read_b128; 144-B lane stride =
    // 2-way alias + 4-way bg broadcast, conflict-free per counters).
#define DSREAD_W(buf, oo_) do {                                                 \
        const char* r_ = (const char*)&ldsW[buf][wv_i][oo_][0] + wg * 144;      \
        _Pragma("unroll")                                                       \
        for (int q_ = 0; q_ < 9; ++q_)                                          \
            wq[q_] = *reinterpret_cast<const vfloat4*>(r_ + q_ * 16);           \
    } while (0)

#define WQ(t) (wq[(t) >> 2][(t) & 3])

    // issue 3 float4 rows of batch b0+bi_ for channel cidx into slot s_
#define XLD(s_, cidx, bi_) do {                                                 \
        const char* p_ = xb0 + (unsigned)(bi_) * 524288u                        \
                         + (unsigned)(cidx) * 16384u;                           \
        xv##s_[0] = *reinterpret_cast<const float4*>(p_);                       \
        xv##s_[1] = *reinterpret_cast<const float4*>(p_ + 256);                 \
        xv##s_[2] = *reinterpret_cast<const float4*>(p_ + 512);                 \
    } while (0)

    // expand slot s_ via DPP halo, 36 FMAs into ACC[bi_]
#define FMA1(ACC, s_, bi_) do {                                                 \
        float xr_[3][6];                                                        \
        _Pragma("unroll")                                                       \
        for (int r_ = 0; r_ < 3; ++r_) {                                        \
            xr_[r_][0] = xv##s_[r_].x; xr_[r_][1] = xv##s_[r_].y;               \
            xr_[r_][2] = xv##s_[r_].z; xr_[r_][3] = xv##s_[r_].w;               \
            xr_[r_][4] = dpp_nextlane(xv##s_[r_].x);                            \
            xr_[r_][5] = dpp_nextlane(xv##s_[r_].y);                            \
        }                                                                       \
        _Pragma("unroll")                                                       \
        for (int wi_ = 0; wi_ < 4; ++wi_)                                       \
        _Pragma("unroll")                                                       \
        for (int ii_ = 0; ii_ < 3; ++ii_)                                       \
        _Pragma("unroll")                                                       \
        for (int j_ = 0; j_ < 3; ++j_)                                          \
            ACC[bi_][wi_] = fmaf(xr_[ii_][wi_ + j_],                            \
                                 WQ(wi_ * 9 + ii_ * 3 + j_), ACC[bi_][wi_]);    \
    } while (0)

    vfloat4 wq[9];
    float4  xvA[3], xvB[3], xvC[3], xvD[3];

    // ---- prologue: depth-2 W prefetch, then x(0) as the oldest-next VMEM
    STAGE_W2(0, 0);
    STAGE_W2(1, 1);
    XLD(A, 0, 0);
    XLD(B, 0, 1);
    XLD(C, 0, 2);
    XLD(D, 0, 3);

    for (int c = 0; c < C_; ++c) {
        const int p = c & 1;
        // invariant: outstanding = gll(c) 18 + x(c) 12 + gll(c+1) 18 = 48.
        // vmcnt(30) retires exactly gll(c) (2 channels old -> ~free).
        WAITV(30);
        DSREAD_W(p, 0);                   // wq := o0 row
        FENCE();
        __builtin_amdgcn_s_setprio(1);    // favor FMA waves on the scheduler
        FMA1(acc0, A, 0);                 // waits x(c) only (oldest in queue)
        FMA1(acc0, B, 1);
        FMA1(acc0, C, 2);
        FMA1(acc0, D, 3);
        __builtin_amdgcn_s_setprio(0);
        FENCE();
        DSREAD_W(p, 1);                   // wq := o1 row (same regs)
        FENCE();
        __builtin_amdgcn_s_setprio(1);
        FMA1(acc1, A, 0);
        FMA1(acc1, B, 1);
        FMA1(acc1, C, 2);
        FMA1(acc1, D, 3);
        __builtin_amdgcn_s_setprio(0);
        FENCE();
        if (c + 1 < C_) {                 // x(c+1): oldest VMEM of channel c+1
            XLD(A, c + 1, 0);
            XLD(B, c + 1, 1);
            XLD(C, c + 1, 2);
            XLD(D, c + 1, 3);
        }
        FENCE();
        {                                 // gll(c+2): YOUNGEST. Clamped dup at
            const int cn = (c + 2 < C_) ? (c + 2) : (C_ - 1);  // c=30,31 keeps
            STAGE_W2(p, cn);              // the count invariant; buf p was
        }                                 // fully ds_read above (no race).
    }

    // ---- epilogue: bias + nontemporal float2 stores (8B-aligned), 2 o's
#pragma unroll
    for (int oo = 0; oo < 2; ++oo) {
        const int oc = o0 + oo;
        const float* brow = bias + ((long)oc * OH_ + h) * OW_ + w0;
        float2 bv0 = *reinterpret_cast<const float2*>(brow);
        float2 bv1;
        if (full) bv1 = *reinterpret_cast<const float2*>(brow + 2);
        else { bv1.x = 0.f; bv1.y = 0.f; }
#pragma unroll
        for (int bi = 0; bi < 4; ++bi) {
            const float* a_ = oo ? acc1[bi] : acc0[bi];
            float* orow = out + (((long)(b0 + bi) * O_ + oc) * OH_ + h) * OW_ + w0;
            vfloat2 s0; s0.x = a_[0] + bv0.x; s0.y = a_[1] + bv0.y;
            __builtin_nontemporal_store(s0, reinterpret_cast<vfloat2*>(orow));
            if (full) {
                vfloat2 s1; s1.x = a_[2] + bv1.x; s1.y = a_[3] + bv1.y;
                __builtin_nontemporal_store(s1, reinterpret_cast<vfloat2*>(orow) + 1);
            }
        }
    }

#undef STAGE_W2
#undef DSREAD_W
#undef WQ
#undef XLD
#undef FMA1
}

extern "C" void kernel_launch(void* const* d_in, const int* in_sizes, int n_in,
                              void* d_out, int out_size, void* d_ws, size_t ws_size,
                              hipStream_t stream) {
    const float* x    = (const float*)d_in[0];
    const float* Wt   = (const float*)d_in[1];
    const float* bias = (const float*)d_in[2];
    float* out        = (float*)d_out;

    dim3 grid(992);   // (62 h x 8 og x 2 batch-halves), XCD-swizzled
    dim3 block(256);
    lcl_kernel<<<grid, block, 0, stream>>>(x, Wt, bias, out);
}

// Round 25
// 137.306 us; speedup vs baseline: 2.2458x; 1.0402x over previous
//
#include <hip/hip_runtime.h>

// Locally connected layer:
// out[b,o,h,w] = sum_{c,i,j} x[b,c,h+i,w+j] * W[o,c,h,w,i,j] + bias[o,h,w]
// x: [32,32,64,64] f32, W: [64,32,62,62,3,3] f32, bias: [64,62,62] f32
// out: [32,64,62,62] f32
//
// R25 = R21 (best, 140us bench) + WIDE W staging: each 2232-B W row staged
// with 2x global_load_lds dwordx4 (1024 B each) + 1x dword tail covering
// [1976,2232) (overlap [1976,2048) double-written with identical data; no
// OOB: the last W row ends exactly at the buffer end). 18 -> 6 gll instrs
// per wave-channel. Global dwordx4 needs only dword alignment (row starts
// are 8B-aligned at odd h); the 16B requirement is on the LDS side, where
// slot bases are 16B-aligned by construction (alignas + 2304-B slots).
// Queue invariant: gll(c) 6 + x(c) 12 + gll(c+1) 6 = 24 -> WAITV(18)
// retires exactly gll(c) (2 channels old, ~free); FMA's compiler-counted
// vmcnt(6) waits only x(c) (older than gll(c+1)). FIFO-clean (R11 lesson).
// Validated: pin-before-FENCE (R20: VGPR 64->104), x-oldest/gll-youngest
// (R21), batch-split twins (R20), 2 o's/wave, barrier-free (R12), DPP halo
// 0x101 (R8), chunked XCD swizzle (R3), nontemporal stores, plain
// launch_bounds (min-waves clause spills: R4/R8).

#define C_  32
#define B_  32
#define O_  64
#define H_  64
#define W_  64
#define OH_ 62
#define OW_ 62

typedef float vfloat2 __attribute__((ext_vector_type(2)));
typedef float vfloat4 __attribute__((ext_vector_type(4)));

#define GLL16(gaddr, laddr)                                                     \
    __builtin_amdgcn_global_load_lds(                                           \
        (const __attribute__((address_space(1))) void*)(gaddr),                 \
        (__attribute__((address_space(3))) void*)(laddr), 16, 0, 0)

#define GLL4(gaddr, laddr)                                                      \
    __builtin_amdgcn_global_load_lds(                                           \
        (const __attribute__((address_space(1))) void*)(gaddr),                 \
        (__attribute__((address_space(3))) void*)(laddr), 4, 0, 0)

// dst[lane] = src[lane+1] within each 16-lane row (validated R8)
__device__ __forceinline__ float dpp_nextlane(float v) {
    return __int_as_float(__builtin_amdgcn_update_dpp(
        0, __float_as_int(v), 0x101, 0xf, 0xf, true));
}

#define WAITV(n) do {                                                           \
        asm volatile("s_waitcnt vmcnt(" #n ")" ::: "memory");                   \
        __builtin_amdgcn_sched_barrier(0);                                      \
    } while (0)

#define FENCE() __builtin_amdgcn_sched_barrier(0)

__global__ __launch_bounds__(256)
void lcl_kernel(const float* __restrict__ x,
                const float* __restrict__ Wt,
                const float* __restrict__ bias,
                float* __restrict__ out) {
    // W rows: [2 buffers][4 waves][2 o's][576 floats] = 36864 B; slot =
    // 2304 B (16B-multiple), base 16B-aligned for the dwordx4 LDS writes.
    __shared__ __attribute__((aligned(16))) float ldsW[2][4][2][576];

    // ---- chunked XCD swizzle (hw: XCD = blockIdx.x % 8); 992 = 8 * 124
    const int i0      = blockIdx.x;
    const int logical = (i0 & 7) * 124 + (i0 >> 3);
    const int bhalf   = logical & 1;                 // twin: batches 0-15/16-31
    const int pair    = logical >> 1;                // 0..495
    const int og      = pair & 7;                    // o-octet (fast)
    const int h       = pair >> 3;                   // 0..61

    const int wv_i = threadIdx.x >> 6;               // wave 0..3
    const int o0   = (og << 3) + (wv_i << 1);        // this wave: o0, o0+1
    const int lane = threadIdx.x & 63;
    const int wg   = lane & 15;                      // w0 = 4*wg
    const int bg   = lane >> 4;                      // 4 batches per bg
    const int w0   = wg * 4;
    const int b0   = bhalf * 16 + bg * 4;
    const bool full = (wg < 15);                     // wg15 stores only w=60,61

    float acc0[4][4], acc1[4][4];
#pragma unroll
    for (int bi = 0; bi < 4; ++bi)
#pragma unroll
        for (int wi = 0; wi < 4; ++wi) { acc0[bi][wi] = 0.f; acc1[bi][wi] = 0.f; }

    // W row bases (floats): o*C*34596 + h*558
    const long wrow0 = (long)o0 * (C_ * 34596) + (long)h * 558;
    const long wrow1 = wrow0 + (long)C_ * 34596;     // o0+1

    // x byte base for (b0, h, w0)
    const char* xb0 = (const char*)x + (unsigned)b0 * 524288u
                      + (unsigned)h * 256u + (unsigned)wg * 16u;

    // stage one 2232-B W row: 2x dwordx4 gll (1024 B each) + dword tail
    // covering [1976,2232) ([1976,2048) double-written with same data).
#define STAGE_ROW(srow, drow) do {                                              \
        GLL16((srow) + lane * 16, (drow));                                      \
        GLL16((srow) + 1024 + lane * 16, (drow) + 1024);                        \
        GLL4((srow) + 1976 + lane * 4, (drow) + 1976);                          \
    } while (0)

#define STAGE_W2(buf, cidx) do {                                                \
        const char* s0_ = (const char*)(Wt + wrow0 + (long)(cidx) * 34596);     \
        const char* s1_ = (const char*)(Wt + wrow1 + (long)(cidx) * 34596);     \
        char* d0_ = (char*)&ldsW[buf][wv_i][0][0];                              \
        char* d1_ = (char*)&ldsW[buf][wv_i][1][0];                              \
        STAGE_ROW(s0_, d0_);                                                    \
        STAGE_ROW(s1_, d1_);                                                    \
    } while (0)

    // lane's 36 W floats for o-slot oo_ (9 ds_read_b128; 144-B lane stride =
    // 2-way alias + 4-way bg broadcast, conflict-free per counters).
#define DSREAD_W(buf, oo_) do {                                                 \
        const char* r_ = (const char*)&ldsW[buf][wv_i][oo_][0] + wg * 144;      \
        _Pragma("unroll")                                                       \
        for (int q_ = 0; q_ < 9; ++q_)                                          \
            wq[q_] = *reinterpret_cast<const vfloat4*>(r_ + q_ * 16);           \
    } while (0)

#define WQ(t) (wq[(t) >> 2][(t) & 3])

    // issue 3 float4 rows of batch b0+bi_ for channel cidx into slot s_
#define XLD(s_, cidx, bi_) do {                                                 \
        const char* p_ = xb0 + (unsigned)(bi_) * 524288u                        \
                         + (unsigned)(cidx) * 16384u;                           \
        xv##s_[0] = *reinterpret_cast<const float4*>(p_);                       \
        xv##s_[1] = *reinterpret_cast<const float4*>(p_ + 256);                 \
        xv##s_[2] = *reinterpret_cast<const float4*>(p_ + 512);                 \
    } while (0)

    // expand slot s_ via DPP halo, 36 FMAs into ACC[bi_]
#define FMA1(ACC, s_, bi_) do {                                                 \
        float xr_[3][6];                                                        \
        _Pragma("unroll")                                                       \
        for (int r_ = 0; r_ < 3; ++r_) {                                        \
            xr_[r_][0] = xv##s_[r_].x; xr_[r_][1] = xv##s_[r_].y;               \
            xr_[r_][2] = xv##s_[r_].z; xr_[r_][3] = xv##s_[r_].w;               \
            xr_[r_][4] = dpp_nextlane(xv##s_[r_].x);                            \
            xr_[r_][5] = dpp_nextlane(xv##s_[r_].y);                            \
        }                                                                       \
        _Pragma("unroll")                                                       \
        for (int wi_ = 0; wi_ < 4; ++wi_)                                       \
        _Pragma("unroll")                                                       \
        for (int ii_ = 0; ii_ < 3; ++ii_)                                       \
        _Pragma("unroll")                                                       \
        for (int j_ = 0; j_ < 3; ++j_)                                          \
            ACC[bi_][wi_] = fmaf(xr_[ii_][wi_ + j_],                            \
                                 WQ(wi_ * 9 + ii_ * 3 + j_), ACC[bi_][wi_]);    \
    } while (0)

    vfloat4 wq[9];
    float4  xvA[3], xvB[3], xvC[3], xvD[3];

    // ---- prologue: depth-2 W prefetch, then x(0) as the oldest-next VMEM
    STAGE_W2(0, 0);
    STAGE_W2(1, 1);
    XLD(A, 0, 0);
    XLD(B, 0, 1);
    XLD(C, 0, 2);
    XLD(D, 0, 3);

    for (int c = 0; c < C_; ++c) {
        const int p = c & 1;
        // invariant: outstanding = gll(c) 6 + x(c) 12 + gll(c+1) 6 = 24.
        // vmcnt(18) retires exactly gll(c) (2 channels old -> ~free).
        WAITV(18);
        DSREAD_W(p, 0);                   // wq := o0 row
        FENCE();
        FMA1(acc0, A, 0);                 // waits x(c) only (oldest in queue)
        FMA1(acc0, B, 1);
        FMA1(acc0, C, 2);
        FMA1(acc0, D, 3);
        FENCE();
        DSREAD_W(p, 1);                   // wq := o1 row (same regs)
        FENCE();
        FMA1(acc1, A, 0);
        FMA1(acc1, B, 1);
        FMA1(acc1, C, 2);
        FMA1(acc1, D, 3);
        FENCE();
        if (c + 1 < C_) {                 // x(c+1): oldest VMEM of channel c+1
            XLD(A, c + 1, 0);
            XLD(B, c + 1, 1);
            XLD(C, c + 1, 2);
            XLD(D, c + 1, 3);
        }
        FENCE();
        {                                 // gll(c+2): YOUNGEST. Clamped dup at
            const int cn = (c + 2 < C_) ? (c + 2) : (C_ - 1);  // c=30,31 keeps
            STAGE_W2(p, cn);              // the count invariant; buf p was
        }                                 // fully ds_read above (no race).
    }

    // ---- epilogue: bias + nontemporal float2 stores (8B-aligned), 2 o's
#pragma unroll
    for (int oo = 0; oo < 2; ++oo) {
        const int oc = o0 + oo;
        const float* brow = bias + ((long)oc * OH_ + h) * OW_ + w0;
        float2 bv0 = *reinterpret_cast<const float2*>(brow);
        float2 bv1;
        if (full) bv1 = *reinterpret_cast<const float2*>(brow + 2);
        else { bv1.x = 0.f; bv1.y = 0.f; }
#pragma unroll
        for (int bi = 0; bi < 4; ++bi) {
            const float* a_ = oo ? acc1[bi] : acc0[bi];
            float* orow = out + (((long)(b0 + bi) * O_ + oc) * OH_ + h) * OW_ + w0;
            vfloat2 s0; s0.x = a_[0] + bv0.x; s0.y = a_[1] + bv0.y;
            __builtin_nontemporal_store(s0, reinterpret_cast<vfloat2*>(orow));
            if (full) {
                vfloat2 s1; s1.x = a_[2] + bv1.x; s1.y = a_[3] + bv1.y;
                __builtin_nontemporal_store(s1, reinterpret_cast<vfloat2*>(orow) + 1);
            }
        }
    }

#undef STAGE_ROW
#undef STAGE_W2
#undef DSREAD_W
#undef WQ
#undef XLD
#undef FMA1
}

extern "C" void kernel_launch(void* const* d_in, const int* in_sizes, int n_in,
                              void* d_out, int out_size, void* d_ws, size_t ws_size,
                              hipStream_t stream) {
    const float* x    = (const float*)d_in[0];
    const float* Wt   = (const float*)d_in[1];
    const float* bias = (const float*)d_in[2];
    float* out        = (float*)d_out;

    dim3 grid(992);   // (62 h x 8 og x 2 batch-halves), XCD-swizzled
    dim3 block(256);
    lcl_kernel<<<grid, block, 0, stream>>>(x, Wt, bias, out);
}